// Round 2
// baseline (74910.321 us; speedup 1.0000x reference)
//
#include <hip/hip_runtime.h>
#include <math.h>

#define BATCH 128
#define TT    12
#define CIN   10
#define HID   64
#define CTOT  74            // CIN + HID
#define OC    256           // 4*HID gate channels
#define KK    666           // CTOT*9
#define PLANE 625           // 25*25
#define HSZ   (BATCH*HID*PLANE)   // 5,120,000 floats per state buffer
#define NCHUNK 37           // CTOT/2 channels per chunk
#define CHUNK_FLOATS 4608   // 2 ch * 9 * 256 gate-weights
#define WRE_FLOATS (OC*KK)  // 170,496 (+512 slack for dummy prefetch calls)

__device__ __forceinline__ float fsigm(float v)  { return 1.f / (1.f + __expf(-v)); }
__device__ __forceinline__ float ftanh(float v)  { return 1.f - 2.f / (__expf(2.f*v) + 1.f); }

// -------- reorder conv_w (256,74,3,3) -> wre[(i*9+koff)*256 + j*4 + g] --------
__global__ void k_reorder(const float* __restrict__ w, float* __restrict__ wre) {
    int tid = blockIdx.x * 256 + threadIdx.x;
    if (tid >= OC * KK) return;
    int ik  = tid >> 8;          // (i*9 + koff) in [0,666)
    int rem = tid & 255;
    int j   = rem >> 2;
    int g   = rem & 3;
    wre[tid] = w[(g * HID + j) * KK + ik];
}

// -------- fused conv(3x3, 74ch -> 256ch) + LSTM pointwise, one timestep --------
// block = (row-tile rt, batch b), 320 thr = 5 waves; wave = output row, lane = hid ch j.
// Double-buffered 2-channel chunks: weights via global_load_lds (async, drained by the
// next __syncthreads), input halo via 2 clamped reg loads + late ds_write.
__global__ __launch_bounds__(320, 4) void k_step(
    const float* __restrict__ x, const float* __restrict__ wre,
    const float* __restrict__ bias, const float* __restrict__ hprev,
    float* __restrict__ hnext, float* __restrict__ cbuf, int t)
{
    __shared__ __align__(16) float4 wls[2][1280];   // 18KB real + dummy pad, x2 buf
    __shared__ __align__(16) float  itile[2][392];  // 2ch x [7][28] rows, x2 buf

    const int tid  = threadIdx.x;
    const int rt   = blockIdx.x;             // row tile 0..4
    const int b    = blockIdx.y;             // batch
    const int r0   = rt * 5;
    const int wave = tid >> 6;                // 0..4 -> output row r0+wave
    const int lane = tid & 63;
    const int j    = lane;                    // hid channel

    const float* xt = x + (size_t)(b * TT + t) * CIN * PLANE;
    const float* hp = hprev + (size_t)b * HID * PLANE;

    // ---- precompute staging coords (loop-invariant per thread) ----
    int  s_ch2[2], s_off[2];
    bool s_ok[2];
    #pragma unroll
    for (int s = 0; s < 2; ++s) {
        int idx = tid + s * 320;
        int ch2 = idx / 196;                  // 0..3 (>=2 only for dummy lanes)
        int rem = idx - ch2 * 196;
        int rr  = rem / 28;
        int cc  = rem - rr * 28;
        int gr  = r0 + rr - 1, gc = cc - 1;
        bool ok = ((unsigned)gr < 25u) && ((unsigned)gc < 25u) && (idx < 392);
        s_ch2[s] = ch2;
        s_off[s] = ok ? (gr * 25 + gc) : 0;
        s_ok[s]  = ok;
    }

    // clamped, unconditional input loads for chunk kn (channels 2kn, 2kn+1)
    auto load_inp = [&](int kn, int s) -> float {
        int ch = 2 * kn + s_ch2[s];
        if (ch > CTOT - 1) ch = CTOT - 1;
        const float* basep = (ch < CIN) ? (xt + (size_t)ch * PLANE)
                                        : (hp + (size_t)(ch - CIN) * PLANE);
        float v = basep[s_off[s]];
        return s_ok[s] ? v : 0.f;
    };
    auto store_inp = [&](int kn, float v0, float v1) {
        const int nb = kn & 1;
        itile[nb][tid] = v0;                  // tid < 392 always
        if (tid + 320 < 392) itile[nb][tid + 320] = v1;
    };
    // async weight staging: 20 one-KB wave-calls (18 real + 2 dummy), 4 per wave
    auto issue_wgt = [&](int kn) {
        const int nb = kn & 1;
        const float* gbase = wre + (size_t)kn * CHUNK_FLOATS + lane * 4;
        #pragma unroll
        for (int c4 = 0; c4 < 4; ++c4) {
            const int cc = wave * 4 + c4;     // 0..19
            __builtin_amdgcn_global_load_lds(
                (const __attribute__((address_space(1))) void*)(gbase + cc * 256),
                (__attribute__((address_space(3))) void*)&wls[nb][cc * 64],
                16, 0, 0);
        }
    };

    float a0[25], a1[25], a2[25], a3[25];
    #pragma unroll
    for (int p = 0; p < 25; ++p) { a0[p] = 0.f; a1[p] = 0.f; a2[p] = 0.f; a3[p] = 0.f; }

    // ---- prologue: stage chunk 0 ----
    {
        float v0 = load_inp(0, 0), v1 = load_inp(0, 1);
        issue_wgt(0);
        store_inp(0, v0, v1);
    }

    for (int k = 0; k < NCHUNK; ++k) {
        __syncthreads();                       // drains wgt k (vmcnt 0) + inp k ds_writes
        const int kb = k & 1;
        float jv0 = 0.f, jv1 = 0.f;
        if (k < NCHUNK - 1) {                  // prefetch chunk k+1 into other buffer
            jv0 = load_inp(k + 1, 0);
            jv1 = load_inp(k + 1, 1);
            issue_wgt(k + 1);                  // in flight across the whole compute phase
        }

        #pragma unroll
        for (int ch2 = 0; ch2 < 2; ++ch2) {
            #pragma unroll
            for (int ky = 0; ky < 3; ++ky) {
                const float4* wp = &wls[kb][(ch2 * 9 + ky * 3) * 64 + j];
                float4 w0 = wp[0], w1 = wp[64], w2 = wp[128];
                const float4* itr = (const float4*)&itile[kb][ch2 * 196 + (wave + ky) * 28];
                #pragma unroll
                for (int g7 = 0; g7 < 7; ++g7) {
                    float4 v4 = itr[g7];       // broadcast ds_read_b128
                    #pragma unroll
                    for (int e = 0; e < 4; ++e) {
                        const int c = g7 * 4 + e;
                        float v = (e == 0) ? v4.x : (e == 1) ? v4.y : (e == 2) ? v4.z : v4.w;
                        #pragma unroll
                        for (int kx = 0; kx < 3; ++kx) {
                            const int p = c - kx;
                            if (p >= 0 && p < 25) {
                                const float4 w = (kx == 0) ? w0 : (kx == 1) ? w1 : w2;
                                a0[p] = fmaf(v, w.x, a0[p]);
                                a1[p] = fmaf(v, w.y, a1[p]);
                                a2[p] = fmaf(v, w.z, a2[p]);
                                a3[p] = fmaf(v, w.w, a3[p]);
                            }
                        }
                    }
                }
            }
        }

        if (k < NCHUNK - 1) store_inp(k + 1, jv0, jv1);
    }

    // ---- LSTM pointwise update for (b, j, row r0+wave, cols 0..24) ----
    const float bi = bias[j], bf = bias[HID + j], bo = bias[2 * HID + j], bg = bias[3 * HID + j];
    const int   r    = r0 + wave;
    const int   base = (b * HID + j) * PLANE + r * 25;
    float* cp = cbuf  + base;
    float* hn = hnext + base;
    #pragma unroll
    for (int p = 0; p < 25; ++p) {
        float iv = fsigm(a0[p] + bi);
        float fv = fsigm(a1[p] + bf);
        float ov = fsigm(a2[p] + bo);
        float gv = ftanh(a3[p] + bg);
        float cn = fv * cp[p] + iv * gv;
        cp[p] = cn;
        hn[p] = ov * ftanh(cn);
    }
}

// -------- MLP head: relu(h) -> 16 -> 8 -> 2 -> log_softmax --------
__global__ __launch_bounds__(256) void k_mlp(
    const float* __restrict__ hfin,
    const float* __restrict__ w1, const float* __restrict__ b1,
    const float* __restrict__ w2, const float* __restrict__ b2,
    const float* __restrict__ w3, const float* __restrict__ b3,
    float* __restrict__ out)
{
    __shared__ float red[256][17];
    __shared__ float hid1[16];
    __shared__ float hid2[8];
    const int b = blockIdx.x, tid = threadIdx.x;

    float acc[16];
    #pragma unroll
    for (int i = 0; i < 16; ++i) acc[i] = 0.f;

    const float* hb = hfin + (size_t)b * (HID * PLANE);
    for (int k = tid; k < HID * PLANE; k += 256) {
        float hv = hb[k];
        hv = hv > 0.f ? hv : 0.f;
        const float* wf = w1 + (size_t)k * 16;
        #pragma unroll
        for (int i = 0; i < 16; ++i) acc[i] = fmaf(hv, wf[i], acc[i]);
    }
    #pragma unroll
    for (int i = 0; i < 16; ++i) red[tid][i] = acc[i];
    __syncthreads();

    if (tid < 16) {
        float s = b1[tid];
        for (int t2 = 0; t2 < 256; ++t2) s += red[t2][tid];
        hid1[tid] = s > 0.f ? s : 0.f;
    }
    __syncthreads();
    if (tid < 8) {
        float s = b2[tid];
        #pragma unroll
        for (int k2 = 0; k2 < 16; ++k2) s += hid1[k2] * w2[k2 * 8 + tid];
        hid2[tid] = s > 0.f ? s : 0.f;
    }
    __syncthreads();
    if (tid == 0) {
        float l0 = b3[0], l1 = b3[1];
        #pragma unroll
        for (int k3 = 0; k3 < 8; ++k3) { l0 += hid2[k3] * w3[k3 * 2]; l1 += hid2[k3] * w3[k3 * 2 + 1]; }
        float m   = fmaxf(l0, l1);
        float lse = m + logf(__expf(l0 - m) + __expf(l1 - m));
        out[b * 2 + 0] = l0 - lse;
        out[b * 2 + 1] = l1 - lse;
    }
}

extern "C" void kernel_launch(void* const* d_in, const int* in_sizes, int n_in,
                              void* d_out, int out_size, void* d_ws, size_t ws_size,
                              hipStream_t stream) {
    const float* x      = (const float*)d_in[0];
    const float* conv_w = (const float*)d_in[1];
    const float* conv_b = (const float*)d_in[2];
    const float* w1     = (const float*)d_in[3];
    const float* b1     = (const float*)d_in[4];
    const float* w2     = (const float*)d_in[5];
    const float* b2     = (const float*)d_in[6];
    const float* w3     = (const float*)d_in[7];
    const float* b3     = (const float*)d_in[8];
    float* out = (float*)d_out;

    float* h0  = (float*)d_ws;          // ping-pong hidden state
    float* h1  = h0 + HSZ;
    float* c   = h1 + HSZ;              // cell state (in-place)
    float* wre = c + HSZ;               // reordered conv weights (+512 floats slack)

    // ws is poisoned 0xAA and not re-poisoned between replays -> zero state every call
    hipMemsetAsync(h0, 0, (size_t)HSZ * sizeof(float), stream);
    hipMemsetAsync(c,  0, (size_t)HSZ * sizeof(float), stream);

    k_reorder<<<dim3((OC * KK) / 256), dim3(256), 0, stream>>>(conv_w, wre);

    for (int t = 0; t < TT; ++t) {
        float* hp = (t & 1) ? h1 : h0;
        float* hn = (t & 1) ? h0 : h1;
        k_step<<<dim3(5, BATCH), dim3(320), 0, stream>>>(x, wre, conv_b, hp, hn, c, t);
    }
    // after t=11, final h is in h0
    k_mlp<<<dim3(BATCH), dim3(256), 0, stream>>>(h0, w1, b1, w2, b2, w3, b3, out);
}

// Round 3
// 17072.015 us; speedup vs baseline: 4.3879x; 4.3879x over previous
//
#include <hip/hip_runtime.h>
#include <math.h>

#define BATCH 128
#define TT    12
#define CIN   10
#define HID   64
#define CTOT  74            // CIN + HID
#define OC    256           // 4*HID gate channels
#define KK    666           // CTOT*9
#define PLANE 625           // 25*25
#define HSZ   (BATCH*HID*PLANE)   // 5,120,000 floats per state buffer
#define NCHUNK 37           // CTOT/2 channels per chunk
#define CHUNK_FLOATS 4608   // 2 ch * 9 * 256 gate-weights

__device__ __forceinline__ float fsigm(float v)  { return 1.f / (1.f + __expf(-v)); }
__device__ __forceinline__ float ftanh(float v)  { return 1.f - 2.f / (__expf(2.f*v) + 1.f); }

// -------- reorder conv_w (256,74,3,3) -> wre[(i*9+koff)*256 + j*4 + g] --------
__global__ void k_reorder(const float* __restrict__ w, float* __restrict__ wre) {
    int tid = blockIdx.x * 256 + threadIdx.x;
    if (tid >= OC * KK) return;
    int ik  = tid >> 8;          // (i*9 + koff) in [0,666)
    int rem = tid & 255;
    int j   = rem >> 2;
    int g   = rem & 3;
    wre[tid] = w[(g * HID + j) * KK + ik];
}

// -------- fused conv(3x3, 74ch -> 256ch) + LSTM pointwise, one timestep --------
// block = (row-tile rt, batch b), 320 thr = 5 waves; wave = output row, lane = hid ch j.
// Double-buffered 2-channel chunks: weights via global_load_lds (async, drained by the
// next __syncthreads), input halo via 2 clamped reg loads + late ds_write.
// NOTE: no min-waves in launch_bounds — capping VGPR at 128 spills the 100-reg
// accumulator to scratch (round-2 post-mortem: 26 GB scratch traffic, 50x slower).
__global__ __launch_bounds__(320) void k_step(
    const float* __restrict__ x, const float* __restrict__ wre,
    const float* __restrict__ bias, const float* __restrict__ hprev,
    float* __restrict__ hnext, float* __restrict__ cbuf, int t)
{
    __shared__ __align__(16) float4 wls[2][1152];   // 18KB per buf
    __shared__ __align__(16) float  itile[2][392];  // 2ch x [7][28] rows per buf

    const int tid  = threadIdx.x;
    const int rt   = blockIdx.x;             // row tile 0..4
    const int b    = blockIdx.y;             // batch
    const int r0   = rt * 5;
    const int wave = tid >> 6;                // 0..4 -> output row r0+wave
    const int lane = tid & 63;
    const int j    = lane;                    // hid channel

    const float* xt = x + (size_t)(b * TT + t) * CIN * PLANE;
    const float* hp = hprev + (size_t)b * HID * PLANE;

    // ---- precompute staging coords (loop-invariant per thread) ----
    int  s_ch2[2], s_off[2];
    bool s_ok[2];
    #pragma unroll
    for (int s = 0; s < 2; ++s) {
        int idx = tid + s * 320;
        int ch2 = idx / 196;                  // 0..1 real (up to 3 for dead lanes)
        int rem = idx - ch2 * 196;
        int rr  = rem / 28;
        int cc  = rem - rr * 28;
        int gr  = r0 + rr - 1, gc = cc - 1;
        bool ok = ((unsigned)gr < 25u) && ((unsigned)gc < 25u) && (idx < 392);
        s_ch2[s] = (ch2 > 1) ? 1 : ch2;
        s_off[s] = ok ? (gr * 25 + gc) : 0;
        s_ok[s]  = ok;
    }

    // clamped, unconditional input loads for chunk kn (channels 2kn, 2kn+1)
    auto load_inp = [&](int kn, int s) -> float {
        int ch = 2 * kn + s_ch2[s];
        if (ch > CTOT - 1) ch = CTOT - 1;
        const float* basep = (ch < CIN) ? (xt + (size_t)ch * PLANE)
                                        : (hp + (size_t)(ch - CIN) * PLANE);
        float v = basep[s_off[s]];
        return s_ok[s] ? v : 0.f;
    };
    auto store_inp = [&](int kn, float v0, float v1) {
        const int nb = kn & 1;
        itile[nb][tid] = v0;                  // tid < 392 always (392 > 320)
        if (tid + 320 < 392) itile[nb][tid + 320] = v1;
    };
    // async weight staging: 18 one-KB wave-calls (waves 0..3: 4 each, wave 4: 2)
    auto issue_wgt = [&](int kn) {
        const int nb = kn & 1;
        const float* gbase = wre + (size_t)kn * CHUNK_FLOATS + lane * 4;
        #pragma unroll
        for (int c4 = 0; c4 < 4; ++c4) {
            const int cc = wave * 4 + c4;     // 0..19, real 0..17
            if (cc < 18) {
                __builtin_amdgcn_global_load_lds(
                    (const __attribute__((address_space(1))) void*)(gbase + cc * 256),
                    (__attribute__((address_space(3))) void*)&wls[nb][cc * 64],
                    16, 0, 0);
            }
        }
    };

    float a0[25], a1[25], a2[25], a3[25];
    #pragma unroll
    for (int p = 0; p < 25; ++p) { a0[p] = 0.f; a1[p] = 0.f; a2[p] = 0.f; a3[p] = 0.f; }

    // ---- prologue: stage chunk 0 ----
    {
        float v0 = load_inp(0, 0), v1 = load_inp(0, 1);
        issue_wgt(0);
        store_inp(0, v0, v1);
    }

    for (int k = 0; k < NCHUNK; ++k) {
        __syncthreads();                       // drains wgt k (vmcnt 0) + inp k ds_writes
        const int kb = k & 1;
        float jv0 = 0.f, jv1 = 0.f;
        if (k < NCHUNK - 1) {                  // prefetch chunk k+1 into other buffer
            jv0 = load_inp(k + 1, 0);
            jv1 = load_inp(k + 1, 1);
            issue_wgt(k + 1);                  // in flight across the whole compute phase
        }

        #pragma unroll
        for (int ch2 = 0; ch2 < 2; ++ch2) {
            #pragma unroll
            for (int ky = 0; ky < 3; ++ky) {
                const float4* wp = &wls[kb][(ch2 * 9 + ky * 3) * 64 + j];
                float4 w0 = wp[0], w1 = wp[64], w2 = wp[128];
                float row[28];
                const float4* itr = (const float4*)&itile[kb][ch2 * 196 + (wave + ky) * 28];
                #pragma unroll
                for (int g7 = 0; g7 < 7; ++g7) {   // 7x broadcast ds_read_b128
                    float4 v4 = itr[g7];
                    row[g7 * 4 + 0] = v4.x; row[g7 * 4 + 1] = v4.y;
                    row[g7 * 4 + 2] = v4.z; row[g7 * 4 + 3] = v4.w;
                }
                #pragma unroll
                for (int kx = 0; kx < 3; ++kx) {
                    const float4 w = (kx == 0) ? w0 : (kx == 1) ? w1 : w2;
                    #pragma unroll
                    for (int p = 0; p < 25; ++p) {
                        a0[p] = fmaf(row[p + kx], w.x, a0[p]);
                        a1[p] = fmaf(row[p + kx], w.y, a1[p]);
                        a2[p] = fmaf(row[p + kx], w.z, a2[p]);
                        a3[p] = fmaf(row[p + kx], w.w, a3[p]);
                    }
                }
            }
        }

        if (k < NCHUNK - 1) store_inp(k + 1, jv0, jv1);
    }

    // ---- LSTM pointwise update for (b, j, row r0+wave, cols 0..24) ----
    const float bi = bias[j], bf = bias[HID + j], bo = bias[2 * HID + j], bg = bias[3 * HID + j];
    const int   r    = r0 + wave;
    const int   base = (b * HID + j) * PLANE + r * 25;
    float* cp = cbuf  + base;
    float* hn = hnext + base;
    #pragma unroll
    for (int p = 0; p < 25; ++p) {
        float iv = fsigm(a0[p] + bi);
        float fv = fsigm(a1[p] + bf);
        float ov = fsigm(a2[p] + bo);
        float gv = ftanh(a3[p] + bg);
        float cn = fv * cp[p] + iv * gv;
        cp[p] = cn;
        hn[p] = ov * ftanh(cn);
    }
}

// -------- MLP head: relu(h) -> 16 -> 8 -> 2 -> log_softmax --------
__global__ __launch_bounds__(256) void k_mlp(
    const float* __restrict__ hfin,
    const float* __restrict__ w1, const float* __restrict__ b1,
    const float* __restrict__ w2, const float* __restrict__ b2,
    const float* __restrict__ w3, const float* __restrict__ b3,
    float* __restrict__ out)
{
    __shared__ float red[256][17];
    __shared__ float hid1[16];
    __shared__ float hid2[8];
    const int b = blockIdx.x, tid = threadIdx.x;

    float acc[16];
    #pragma unroll
    for (int i = 0; i < 16; ++i) acc[i] = 0.f;

    const float* hb = hfin + (size_t)b * (HID * PLANE);
    for (int k = tid; k < HID * PLANE; k += 256) {
        float hv = hb[k];
        hv = hv > 0.f ? hv : 0.f;
        const float* wf = w1 + (size_t)k * 16;
        #pragma unroll
        for (int i = 0; i < 16; ++i) acc[i] = fmaf(hv, wf[i], acc[i]);
    }
    #pragma unroll
    for (int i = 0; i < 16; ++i) red[tid][i] = acc[i];
    __syncthreads();

    if (tid < 16) {
        float s = b1[tid];
        for (int t2 = 0; t2 < 256; ++t2) s += red[t2][tid];
        hid1[tid] = s > 0.f ? s : 0.f;
    }
    __syncthreads();
    if (tid < 8) {
        float s = b2[tid];
        #pragma unroll
        for (int k2 = 0; k2 < 16; ++k2) s += hid1[k2] * w2[k2 * 8 + tid];
        hid2[tid] = s > 0.f ? s : 0.f;
    }
    __syncthreads();
    if (tid == 0) {
        float l0 = b3[0], l1 = b3[1];
        #pragma unroll
        for (int k3 = 0; k3 < 8; ++k3) { l0 += hid2[k3] * w3[k3 * 2]; l1 += hid2[k3] * w3[k3 * 2 + 1]; }
        float m   = fmaxf(l0, l1);
        float lse = m + logf(__expf(l0 - m) + __expf(l1 - m));
        out[b * 2 + 0] = l0 - lse;
        out[b * 2 + 1] = l1 - lse;
    }
}

extern "C" void kernel_launch(void* const* d_in, const int* in_sizes, int n_in,
                              void* d_out, int out_size, void* d_ws, size_t ws_size,
                              hipStream_t stream) {
    const float* x      = (const float*)d_in[0];
    const float* conv_w = (const float*)d_in[1];
    const float* conv_b = (const float*)d_in[2];
    const float* w1     = (const float*)d_in[3];
    const float* b1     = (const float*)d_in[4];
    const float* w2     = (const float*)d_in[5];
    const float* b2     = (const float*)d_in[6];
    const float* w3     = (const float*)d_in[7];
    const float* b3     = (const float*)d_in[8];
    float* out = (float*)d_out;

    float* h0  = (float*)d_ws;          // ping-pong hidden state
    float* h1  = h0 + HSZ;
    float* c   = h1 + HSZ;              // cell state (in-place)
    float* wre = c + HSZ;               // reordered conv weights

    // ws is poisoned 0xAA and not re-poisoned between replays -> zero state every call
    hipMemsetAsync(h0, 0, (size_t)HSZ * sizeof(float), stream);
    hipMemsetAsync(c,  0, (size_t)HSZ * sizeof(float), stream);

    k_reorder<<<dim3((OC * KK) / 256), dim3(256), 0, stream>>>(conv_w, wre);

    for (int t = 0; t < TT; ++t) {
        float* hp = (t & 1) ? h1 : h0;
        float* hn = (t & 1) ? h0 : h1;
        k_step<<<dim3(5, BATCH), dim3(320), 0, stream>>>(x, wre, conv_b, hp, hn, c, t);
    }
    // after t=11, final h is in h0
    k_mlp<<<dim3(BATCH), dim3(256), 0, stream>>>(h0, w1, b1, w2, b2, w3, b3, out);
}

// Round 4
// 10677.911 us; speedup vs baseline: 7.0154x; 1.5988x over previous
//
#include <hip/hip_runtime.h>
#include <math.h>

#define BATCH 128
#define TT    12
#define CIN   10
#define HID   64
#define CTOT  74            // CIN + HID
#define OC    256           // 4*HID gate channels
#define KK    666           // CTOT*9
#define PLANE 625           // 25*25
#define HSZ   (BATCH*HID*PLANE)   // 5,120,000 floats per state buffer
#define NCHUNK 37           // chunks of 2 input channels
#define CHUNK_FLOATS 4608   // 2 ch * 9 * 256 gate-weights

__device__ __forceinline__ float fsigm(float v)  { return 1.f / (1.f + __expf(-v)); }
__device__ __forceinline__ float ftanh(float v)  { return 1.f - 2.f / (__expf(2.f*v) + 1.f); }

// -------- reorder conv_w (256,74,3,3) -> wre[(i*9+koff)*256 + j*4 + g] --------
__global__ void k_reorder(const float* __restrict__ w, float* __restrict__ wre) {
    int tid = blockIdx.x * 256 + threadIdx.x;
    if (tid >= OC * KK) return;
    int ik  = tid >> 8;          // (i*9 + koff) in [0,666)
    int rem = tid & 255;
    int j   = rem >> 2;
    int g   = rem & 3;
    wre[tid] = w[(g * HID + j) * KK + ik];
}

// -------- fused conv(3x3, 74ch -> 256ch) + LSTM pointwise, one timestep --------
// TWO-PASS column split: pass 0 -> output cols 0..11, pass 1 -> cols 12..24.
// acc[4][13] = 52 regs (vs 100 single-pass) keeps total demand ~105 < 128 so the
// kernel stays in the 16-waves/CU VGPR class with ZERO spill (rounds 2/3 post-
// mortem: >128 demand memory-spills, 26 GB scratch traffic).
// block = (row-tile rt, batch b), 320 thr = 5 waves; wave = output row, lane = hid ch j.
// Double-buffered 2-channel chunks: weights via async global_load_lds (drained by the
// next __syncthreads), input halo via clamped reg loads + late ds_write.
__global__ __launch_bounds__(320, 3) void k_step(
    const float* __restrict__ x, const float* __restrict__ wre,
    const float* __restrict__ bias, const float* __restrict__ hprev,
    float* __restrict__ hnext, float* __restrict__ cbuf, int t)
{
    __shared__ __align__(16) float4 wls[2][1152];   // 18KB per buf
    __shared__ __align__(16) float  itile[2][392];  // 2ch x [7][28] rows per buf

    const int tid  = threadIdx.x;
    const int rt   = blockIdx.x;             // row tile 0..4
    const int b    = blockIdx.y;             // batch
    const int r0   = rt * 5;
    const int wave = tid >> 6;                // 0..4 -> output row r0+wave
    const int lane = tid & 63;
    const int j    = lane;                    // hid channel

    const float* xt = x + (size_t)(b * TT + t) * CIN * PLANE;
    const float* hp = hprev + (size_t)b * HID * PLANE;

    // ---- precompute staging coords (loop-invariant per thread) ----
    int  s_ch2[2], s_off[2];
    bool s_ok[2];
    #pragma unroll
    for (int s = 0; s < 2; ++s) {
        int idx = tid + s * 320;
        int ch2 = idx / 196;
        int rem = idx - ch2 * 196;
        int rr  = rem / 28;
        int cc  = rem - rr * 28;
        int gr  = r0 + rr - 1, gc = cc - 1;
        bool ok = ((unsigned)gr < 25u) && ((unsigned)gc < 25u) && (idx < 392);
        s_ch2[s] = (ch2 > 1) ? 1 : ch2;
        s_off[s] = ok ? (gr * 25 + gc) : 0;
        s_ok[s]  = ok;
    }

    // clamped, unconditional input loads for chunk kn (channels 2kn, 2kn+1)
    auto load_inp = [&](int kn, int s) -> float {
        int ch = 2 * kn + s_ch2[s];
        const float* basep = (ch < CIN) ? (xt + (size_t)ch * PLANE)
                                        : (hp + (size_t)(ch - CIN) * PLANE);
        float v = basep[s_off[s]];
        return s_ok[s] ? v : 0.f;
    };
    auto store_inp = [&](int nb, float v0, float v1) {
        itile[nb][tid] = v0;                  // tid < 392 always (392 > 320)
        if (tid + 320 < 392) itile[nb][tid + 320] = v1;
    };
    // async weight staging: 18 one-KB wave-calls (waves 0..3: 4 each, wave 4: 2)
    auto issue_wgt = [&](int kn, int nb) {
        const float* gbase = wre + (size_t)kn * CHUNK_FLOATS + lane * 4;
        #pragma unroll
        for (int c4 = 0; c4 < 4; ++c4) {
            const int cc = wave * 4 + c4;     // wave-uniform, real 0..17
            if (cc < 18) {
                __builtin_amdgcn_global_load_lds(
                    (const __attribute__((address_space(1))) void*)(gbase + cc * 256),
                    (__attribute__((address_space(3))) void*)&wls[nb][cc * 64],
                    16, 0, 0);
            }
        }
    };

    float a0[13], a1[13], a2[13], a3[13];
    #pragma unroll
    for (int p = 0; p < 13; ++p) { a0[p] = 0.f; a1[p] = 0.f; a2[p] = 0.f; a3[p] = 0.f; }

    const float bi = bias[j], bf = bias[HID + j], bo = bias[2 * HID + j], bg = bias[3 * HID + j];
    const int   obase = (b * HID + j) * PLANE + (r0 + wave) * 25;

    // LSTM pointwise update for cols [c0, c0+np)
    auto lstm_write = [&](int c0, int np) {
        #pragma unroll
        for (int p = 0; p < 13; ++p) {
            if (p < np) {
                const int c = c0 + p;
                float iv = fsigm(a0[p] + bi);
                float fv = fsigm(a1[p] + bf);
                float ov = fsigm(a2[p] + bo);
                float gv = ftanh(a3[p] + bg);
                float cn = fv * cbuf[obase + c] + iv * gv;
                cbuf[obase + c]  = cn;
                hnext[obase + c] = ov * ftanh(cn);
            }
        }
    };

    // ---- prologue: stage chunk 0 into buffer 0 ----
    {
        float v0 = load_inp(0, 0), v1 = load_inp(0, 1);
        issue_wgt(0, 0);
        store_inp(0, v0, v1);
    }

    for (int it = 0; it < 2 * NCHUNK; ++it) {
        __syncthreads();                       // drains wgt it (vmcnt 0) + inp ds_writes
        const int kb = it & 1;
        float jv0 = 0.f, jv1 = 0.f;
        if (it < 2 * NCHUNK - 1) {             // prefetch next chunk into other buffer
            int kn = it + 1; if (kn >= NCHUNK) kn -= NCHUNK;
            jv0 = load_inp(kn, 0);
            jv1 = load_inp(kn, 1);
            issue_wgt(kn, (it + 1) & 1);       // in flight across the compute phase
        }
        // pass 0 (it<37): padded cols 0..15 (float4 0..3); pass 1: cols 12..27 (float4 3..6)
        const int fbase = (it >= NCHUNK) ? 3 : 0;

        #pragma unroll
        for (int ch2 = 0; ch2 < 2; ++ch2) {
            #pragma unroll
            for (int ky = 0; ky < 3; ++ky) {
                const float4* wp = &wls[kb][(ch2 * 9 + ky * 3) * 64 + j];
                float4 w0 = wp[0], w1 = wp[64], w2 = wp[128];
                float r[16];
                const float4* itr = (const float4*)&itile[kb][ch2 * 196 + (wave + ky) * 28] + fbase;
                #pragma unroll
                for (int q = 0; q < 4; ++q) {   // 4x broadcast ds_read_b128
                    float4 v4 = itr[q];
                    r[q * 4 + 0] = v4.x; r[q * 4 + 1] = v4.y;
                    r[q * 4 + 2] = v4.z; r[q * 4 + 3] = v4.w;
                }
                #pragma unroll
                for (int kx = 0; kx < 3; ++kx) {
                    const float4 w = (kx == 0) ? w0 : (kx == 1) ? w1 : w2;
                    #pragma unroll
                    for (int p = 0; p < 13; ++p) {   // compile-time reg indices only
                        a0[p] = fmaf(r[p + kx], w.x, a0[p]);
                        a1[p] = fmaf(r[p + kx], w.y, a1[p]);
                        a2[p] = fmaf(r[p + kx], w.z, a2[p]);
                        a3[p] = fmaf(r[p + kx], w.w, a3[p]);
                    }
                }
            }
        }

        if (it == NCHUNK - 1) {                // end of pass 0: write cols 0..11, reset
            lstm_write(0, 12);
            #pragma unroll
            for (int p = 0; p < 13; ++p) { a0[p] = 0.f; a1[p] = 0.f; a2[p] = 0.f; a3[p] = 0.f; }
        }
        if (it < 2 * NCHUNK - 1) store_inp((it + 1) & 1, jv0, jv1);
    }
    lstm_write(12, 13);                        // end of pass 1: cols 12..24
}

// -------- MLP head: relu(h) -> 16 -> 8 -> 2 -> log_softmax --------
__global__ __launch_bounds__(256) void k_mlp(
    const float* __restrict__ hfin,
    const float* __restrict__ w1, const float* __restrict__ b1,
    const float* __restrict__ w2, const float* __restrict__ b2,
    const float* __restrict__ w3, const float* __restrict__ b3,
    float* __restrict__ out)
{
    __shared__ float red[256][17];
    __shared__ float hid1[16];
    __shared__ float hid2[8];
    const int b = blockIdx.x, tid = threadIdx.x;

    float acc[16];
    #pragma unroll
    for (int i = 0; i < 16; ++i) acc[i] = 0.f;

    const float* hb = hfin + (size_t)b * (HID * PLANE);
    for (int k = tid; k < HID * PLANE; k += 256) {
        float hv = hb[k];
        hv = hv > 0.f ? hv : 0.f;
        const float* wf = w1 + (size_t)k * 16;
        #pragma unroll
        for (int i = 0; i < 16; ++i) acc[i] = fmaf(hv, wf[i], acc[i]);
    }
    #pragma unroll
    for (int i = 0; i < 16; ++i) red[tid][i] = acc[i];
    __syncthreads();

    if (tid < 16) {
        float s = b1[tid];
        for (int t2 = 0; t2 < 256; ++t2) s += red[t2][tid];
        hid1[tid] = s > 0.f ? s : 0.f;
    }
    __syncthreads();
    if (tid < 8) {
        float s = b2[tid];
        #pragma unroll
        for (int k2 = 0; k2 < 16; ++k2) s += hid1[k2] * w2[k2 * 8 + tid];
        hid2[tid] = s > 0.f ? s : 0.f;
    }
    __syncthreads();
    if (tid == 0) {
        float l0 = b3[0], l1 = b3[1];
        #pragma unroll
        for (int k3 = 0; k3 < 8; ++k3) { l0 += hid2[k3] * w3[k3 * 2]; l1 += hid2[k3] * w3[k3 * 2 + 1]; }
        float m   = fmaxf(l0, l1);
        float lse = m + logf(__expf(l0 - m) + __expf(l1 - m));
        out[b * 2 + 0] = l0 - lse;
        out[b * 2 + 1] = l1 - lse;
    }
}

extern "C" void kernel_launch(void* const* d_in, const int* in_sizes, int n_in,
                              void* d_out, int out_size, void* d_ws, size_t ws_size,
                              hipStream_t stream) {
    const float* x      = (const float*)d_in[0];
    const float* conv_w = (const float*)d_in[1];
    const float* conv_b = (const float*)d_in[2];
    const float* w1     = (const float*)d_in[3];
    const float* b1     = (const float*)d_in[4];
    const float* w2     = (const float*)d_in[5];
    const float* b2     = (const float*)d_in[6];
    const float* w3     = (const float*)d_in[7];
    const float* b3     = (const float*)d_in[8];
    float* out = (float*)d_out;

    float* h0  = (float*)d_ws;          // ping-pong hidden state
    float* h1  = h0 + HSZ;
    float* c   = h1 + HSZ;              // cell state (in-place)
    float* wre = c + HSZ;               // reordered conv weights

    // ws is poisoned 0xAA and not re-poisoned between replays -> zero state every call
    hipMemsetAsync(h0, 0, (size_t)HSZ * sizeof(float), stream);
    hipMemsetAsync(c,  0, (size_t)HSZ * sizeof(float), stream);

    k_reorder<<<dim3((OC * KK) / 256), dim3(256), 0, stream>>>(conv_w, wre);

    for (int t = 0; t < TT; ++t) {
        float* hp = (t & 1) ? h1 : h0;
        float* hn = (t & 1) ? h0 : h1;
        k_step<<<dim3(5, BATCH), dim3(320), 0, stream>>>(x, wre, conv_b, hp, hn, c, t);
    }
    // after t=11, final h is in h0
    k_mlp<<<dim3(BATCH), dim3(256), 0, stream>>>(h0, w1, b1, w2, b2, w3, b3, out);
}

// Round 5
// 5240.837 us; speedup vs baseline: 14.2936x; 2.0374x over previous
//
#include <hip/hip_runtime.h>
#include <math.h>

#define BATCH 128
#define TT    12
#define CIN   10
#define HID   64
#define CTOT  74            // CIN + HID
#define OC    256           // 4*HID gate channels
#define KK    666           // CTOT*9
#define PLANE 625           // 25*25
#define HSZ   (BATCH*HID*PLANE)   // 5,120,000 floats per state buffer
#define NCHUNK 37           // chunks of 2 input channels
#define CHUNK_F4 1152       // 2 ch * 9 * 256 gate-weights / 4 = float4 per chunk

__device__ __forceinline__ float fsigm(float v)  { return 1.f / (1.f + __expf(-v)); }
__device__ __forceinline__ float ftanh(float v)  { return 1.f - 2.f / (__expf(2.f*v) + 1.f); }

// -------- reorder conv_w (256,74,3,3) -> wre[(i*9+koff)*256 + j*4 + g] --------
__global__ void k_reorder(const float* __restrict__ w, float* __restrict__ wre) {
    int tid = blockIdx.x * 256 + threadIdx.x;
    if (tid >= OC * KK) return;
    int ik  = tid >> 8;          // (i*9 + koff) in [0,666)
    int rem = tid & 255;
    int j   = rem >> 2;
    int g   = rem & 3;
    wre[tid] = w[(g * HID + j) * KK + ik];
}

// -------- fused conv(3x3, 74ch -> 256ch) + LSTM pointwise, one timestep --------
// SINGLE-WAVE blocks, NO barriers: block = (row, batch, col-pass), 64 threads = 1 wave,
// lane = hid channel j. Each wave owns one output row and double-buffers its private
// 2-channel input tile (rows row-1..row+1, 28 cols) in LDS; producer == consumer, so
// only compiler lgkmcnt waits — no lockstep (round-4 post-mortem: 74 full-drain
// barriers at 12.5 waves/CU left VALU 71% idle).
// Weights are read per-thread from the reordered global layout (682 KB, L1/L2-resident,
// lane-coalesced dwordx4) — no weight->barrier dependency.
// Column passes: pass 0 -> cols 0..11, pass 1 -> cols 12..24 (acc 52 regs, total ~114).
__global__ __launch_bounds__(64, 4) void k_step(
    const float* __restrict__ x, const float* __restrict__ wre,
    const float* __restrict__ bias, const float* __restrict__ hprev,
    float* __restrict__ hnext, float* __restrict__ cbuf, int t)
{
    __shared__ __align__(16) float itile[2][168];   // [buf][2ch x 3 rows x 28 cols]

    const int j    = threadIdx.x;            // hid channel / lane
    const int row  = blockIdx.x;             // 0..24 output row
    const int b    = blockIdx.y;             // batch
    const int pass = blockIdx.z;             // 0: cols 0..11, 1: cols 12..24

    const float* xt = x + (size_t)(b * TT + t) * CIN * PLANE;
    const float* hp = hprev + (size_t)b * HID * PLANE;

    // ---- precompute staging coords (loop-invariant): 168 floats over 3 rounds ----
    int  s_ch2[3], s_off[3];
    bool s_ok[3];
    #pragma unroll
    for (int s = 0; s < 3; ++s) {
        int idx = j + s * 64;
        int ch2 = idx / 84;                   // 0..1 real (2 for dead lanes)
        int rem = idx - ch2 * 84;
        int rr  = rem / 28;
        int cc  = rem - rr * 28;
        int gr  = row + rr - 1, gc = cc - 1;
        bool ok = ((unsigned)gr < 25u) && ((unsigned)gc < 25u) && (idx < 168);
        s_ch2[s] = (ch2 > 1) ? 1 : ch2;
        s_off[s] = ok ? (gr * 25 + gc) : 0;
        s_ok[s]  = ok;
    }
    auto load_inp = [&](int kn, int s) -> float {
        int ch = 2 * kn + s_ch2[s];
        const float* bp = (ch < CIN) ? (xt + (size_t)ch * PLANE)
                                     : (hp + (size_t)(ch - CIN) * PLANE);
        float v = bp[s_off[s]];
        return s_ok[s] ? v : 0.f;
    };
    auto store_inp = [&](int nb, float v0, float v1, float v2) {
        itile[nb][j]      = v0;
        itile[nb][j + 64] = v1;
        if (j < 40) itile[nb][j + 128] = v2;  // idx in [128,168)
    };

    float a0[13], a1[13], a2[13], a3[13];
    #pragma unroll
    for (int p = 0; p < 13; ++p) { a0[p] = 0.f; a1[p] = 0.f; a2[p] = 0.f; a3[p] = 0.f; }

    const int fbase = pass ? 3 : 0;           // float4 window start within 28-col row
    const float4* wre4 = (const float4*)wre;

    // ---- prologue: stage chunk 0 into buffer 0 ----
    {
        float v0 = load_inp(0, 0), v1 = load_inp(0, 1), v2 = load_inp(0, 2);
        store_inp(0, v0, v1, v2);
    }

    for (int k = 0; k < NCHUNK; ++k) {
        const int kb = k & 1;
        float jv0 = 0.f, jv1 = 0.f, jv2 = 0.f;
        if (k < NCHUNK - 1) {                  // issue next-chunk input loads early
            jv0 = load_inp(k + 1, 0);
            jv1 = load_inp(k + 1, 1);
            jv2 = load_inp(k + 1, 2);
        }
        const float4* wch = wre4 + (size_t)k * CHUNK_F4 + j;

        #pragma unroll 1                       // cap weight-load hoisting (reg budget)
        for (int ch2 = 0; ch2 < 2; ++ch2) {
            #pragma unroll
            for (int ky = 0; ky < 3; ++ky) {
                const float4* wp = wch + (ch2 * 9 + ky * 3) * 64;
                float4 w0 = wp[0], w1 = wp[64], w2 = wp[128];   // L1/L2 dwordx4
                float r[16];
                const float4* itr = (const float4*)&itile[kb][ch2 * 84 + ky * 28] + fbase;
                #pragma unroll
                for (int q = 0; q < 4; ++q) {   // 4x broadcast ds_read_b128
                    float4 v4 = itr[q];
                    r[q * 4 + 0] = v4.x; r[q * 4 + 1] = v4.y;
                    r[q * 4 + 2] = v4.z; r[q * 4 + 3] = v4.w;
                }
                #pragma unroll
                for (int kx = 0; kx < 3; ++kx) {
                    const float4 w = (kx == 0) ? w0 : (kx == 1) ? w1 : w2;
                    #pragma unroll
                    for (int p = 0; p < 13; ++p) {   // compile-time reg indices only
                        a0[p] = fmaf(r[p + kx], w.x, a0[p]);
                        a1[p] = fmaf(r[p + kx], w.y, a1[p]);
                        a2[p] = fmaf(r[p + kx], w.z, a2[p]);
                        a3[p] = fmaf(r[p + kx], w.w, a3[p]);
                    }
                }
            }
        }
        if (k < NCHUNK - 1) store_inp(kb ^ 1, jv0, jv1, jv2);
    }

    // ---- LSTM pointwise update: cols [col0, col0+np) of (b, j, row) ----
    const float bi = bias[j], bf = bias[HID + j], bo = bias[2 * HID + j], bg = bias[3 * HID + j];
    const int col0 = pass ? 12 : 0;
    const int np   = pass ? 13 : 12;
    const int obase = (b * HID + j) * PLANE + row * 25 + col0;
    #pragma unroll
    for (int p = 0; p < 13; ++p) {
        if (p < np) {
            float iv = fsigm(a0[p] + bi);
            float fv = fsigm(a1[p] + bf);
            float ov = fsigm(a2[p] + bo);
            float gv = ftanh(a3[p] + bg);
            float cn = fv * cbuf[obase + p] + iv * gv;
            cbuf[obase + p]  = cn;
            hnext[obase + p] = ov * ftanh(cn);
        }
    }
}

// -------- MLP head: relu(h) -> 16 -> 8 -> 2 -> log_softmax --------
__global__ __launch_bounds__(256) void k_mlp(
    const float* __restrict__ hfin,
    const float* __restrict__ w1, const float* __restrict__ b1,
    const float* __restrict__ w2, const float* __restrict__ b2,
    const float* __restrict__ w3, const float* __restrict__ b3,
    float* __restrict__ out)
{
    __shared__ float red[256][17];
    __shared__ float hid1[16];
    __shared__ float hid2[8];
    const int b = blockIdx.x, tid = threadIdx.x;

    float acc[16];
    #pragma unroll
    for (int i = 0; i < 16; ++i) acc[i] = 0.f;

    const float* hb = hfin + (size_t)b * (HID * PLANE);
    for (int k = tid; k < HID * PLANE; k += 256) {
        float hv = hb[k];
        hv = hv > 0.f ? hv : 0.f;
        const float* wf = w1 + (size_t)k * 16;
        #pragma unroll
        for (int i = 0; i < 16; ++i) acc[i] = fmaf(hv, wf[i], acc[i]);
    }
    #pragma unroll
    for (int i = 0; i < 16; ++i) red[tid][i] = acc[i];
    __syncthreads();

    if (tid < 16) {
        float s = b1[tid];
        for (int t2 = 0; t2 < 256; ++t2) s += red[t2][tid];
        hid1[tid] = s > 0.f ? s : 0.f;
    }
    __syncthreads();
    if (tid < 8) {
        float s = b2[tid];
        #pragma unroll
        for (int k2 = 0; k2 < 16; ++k2) s += hid1[k2] * w2[k2 * 8 + tid];
        hid2[tid] = s > 0.f ? s : 0.f;
    }
    __syncthreads();
    if (tid == 0) {
        float l0 = b3[0], l1 = b3[1];
        #pragma unroll
        for (int k3 = 0; k3 < 8; ++k3) { l0 += hid2[k3] * w3[k3 * 2]; l1 += hid2[k3] * w3[k3 * 2 + 1]; }
        float m   = fmaxf(l0, l1);
        float lse = m + logf(__expf(l0 - m) + __expf(l1 - m));
        out[b * 2 + 0] = l0 - lse;
        out[b * 2 + 1] = l1 - lse;
    }
}

extern "C" void kernel_launch(void* const* d_in, const int* in_sizes, int n_in,
                              void* d_out, int out_size, void* d_ws, size_t ws_size,
                              hipStream_t stream) {
    const float* x      = (const float*)d_in[0];
    const float* conv_w = (const float*)d_in[1];
    const float* conv_b = (const float*)d_in[2];
    const float* w1     = (const float*)d_in[3];
    const float* b1     = (const float*)d_in[4];
    const float* w2     = (const float*)d_in[5];
    const float* b2     = (const float*)d_in[6];
    const float* w3     = (const float*)d_in[7];
    const float* b3     = (const float*)d_in[8];
    float* out = (float*)d_out;

    float* h0  = (float*)d_ws;          // ping-pong hidden state
    float* h1  = h0 + HSZ;
    float* c   = h1 + HSZ;              // cell state (in-place)
    float* wre = c + HSZ;               // reordered conv weights

    // ws is poisoned 0xAA and not re-poisoned between replays -> zero state every call
    hipMemsetAsync(h0, 0, (size_t)HSZ * sizeof(float), stream);
    hipMemsetAsync(c,  0, (size_t)HSZ * sizeof(float), stream);

    k_reorder<<<dim3((OC * KK + 255) / 256), dim3(256), 0, stream>>>(conv_w, wre);

    for (int t = 0; t < TT; ++t) {
        float* hp = (t & 1) ? h1 : h0;
        float* hn = (t & 1) ? h0 : h1;
        k_step<<<dim3(25, BATCH, 2), dim3(64), 0, stream>>>(x, wre, conv_b, hp, hn, c, t);
    }
    // after t=11, final h is in h0
    k_mlp<<<dim3(BATCH), dim3(256), 0, stream>>>(h0, w1, b1, w2, b2, w3, b3, out);
}

// Round 6
// 1315.752 us; speedup vs baseline: 56.9335x; 3.9831x over previous
//
#include <hip/hip_runtime.h>
#include <hip/hip_bf16.h>
#include <math.h>

#define BATCH 128
#define TT    12
#define CIN   10
#define HID   64
#define PLANE 625
#define CH    80          // padded input channels (74 real: 10 x + 64 h + 6 zero)
#define CHS   88          // LDS pixel stride in shorts (176B: 4-way bank pad, 16B aligned)
#define NKB   45          // k-blocks: 9 taps * 5 chunks of 16 ch
#define INPSZ (BATCH*PLANE*CH)    // shorts per inp buffer
#define CSZ   (BATCH*PLANE*HID)   // floats in c / h buffers

typedef __attribute__((ext_vector_type(8)))  short bf16x8;
typedef __attribute__((ext_vector_type(16))) float f32x16;

__device__ __forceinline__ float fsigm(float v){ return 1.f/(1.f+__expf(-v)); }
__device__ __forceinline__ float ftanh(float v){ return 1.f - 2.f/(__expf(2.f*v)+1.f); }
__device__ __forceinline__ unsigned short f2bf(float v){
    __hip_bfloat16 b = __float2bfloat16(v);
    return *reinterpret_cast<unsigned short*>(&b);
}

// ---- prepack conv_w (256,74,3,3) f32 -> B-fragments bf16 ----
// k = tap*80 + ch (tap = ky*3+kx), n-permutation: col = jlo*4 + g  (j = nt*8+jlo, o = g*64+j)
// frag layout (32x32x16 B): lane l: col = l&31, k_local = (l>>5)*8 + e
__global__ void k_wprep(const float* __restrict__ w, unsigned short* __restrict__ wpk){
    int tid = blockIdx.x*256 + threadIdx.x;      // NKB*8*64 = 23040 total
    if (tid >= NKB*8*64) return;
    int lane = tid & 63;
    int nt   = (tid >> 6) & 7;
    int kb   = tid >> 9;
    int tap = kb/5, ci = kb - tap*5;
    int ky = tap/3, kx = tap - ky*3;
    int g = lane & 3, jlo = (lane & 31) >> 2, kh = lane >> 5;
    int o = g*64 + nt*8 + jlo;
    union { unsigned short u[8]; float4 f; } pk;
    #pragma unroll
    for (int e = 0; e < 8; ++e){
        int ch = ci*16 + kh*8 + e;
        float v = (ch < 74) ? w[((o*74 + ch)*3 + ky)*3 + kx] : 0.f;
        pk.u[e] = f2bf(v);
    }
    *reinterpret_cast<float4*>(wpk + (size_t)tid*8) = pk.f;   // idx = (kb*8+nt)*64+lane
}

// ---- copy x_t (f32 NCHW) into inp buffer x-slots (bf16, ch-innermost) ----
__global__ void k_xcopy(const float* __restrict__ x, unsigned short* __restrict__ inp, int t){
    int idx = blockIdx.x*256 + threadIdx.x;      // 128*10*625 = 800000
    if (idx >= BATCH*CIN*PLANE) return;
    int m  = idx % PLANE;
    int r  = idx / PLANE;
    int ch = r % CIN;
    int b  = r / CIN;
    float v = x[((size_t)(b*TT + t)*CIN + ch)*PLANE + m];
    inp[((size_t)b*PLANE + m)*CH + ch] = f2bf(v);
}

// ---- fused conv-as-GEMM (MFMA bf16) + LSTM pointwise, one timestep ----
// block = (mgroup of 128 m-positions, batch), 512 thr = 8 waves; wave = n-tile of 32.
// A: im2col from LDS tile [8 rows][27 cols][88ch-stride]; B: prepacked frags from L2.
// Epilogue: 4-lane shfl_xor exchanges i/f/o/g gates; g==0 lanes update c, write h.
__global__ __launch_bounds__(512) void k_gemm(
    const unsigned short* __restrict__ inp,   // [b][625][80] bf16, step t
    unsigned short* __restrict__ inpn,        // next-step buffer: h-part write
    const unsigned short* __restrict__ wpk,
    const float* __restrict__ bias,           // conv_b[256], o = g*64+j
    float* __restrict__ cbuf,                 // [b][625][64] fp32
    float* __restrict__ hbuf,                 // [b][625][64] fp32 (written when write_h)
    int write_h)
{
    __shared__ __align__(16) unsigned short at[216*CHS];   // 8r*27c pixels, 38 KB

    const int tid  = threadIdx.x;
    const int mg   = blockIdx.x;              // 0..4 (128 m each, m 625..639 pad)
    const int b    = blockIdx.y;
    const int lane = tid & 63;
    const int nt   = tid >> 6;                // wave id = n-tile
    const int r0row = (mg*128)/25;            // 0,5,10,15,20

    // ---- stage A-tile: rows r0row-1..r0row+6, cols -1..25, zero halo/pad ----
    const unsigned short* ib = inp + (size_t)b*PLANE*CH;
    for (int idx = tid; idx < 216*11; idx += 512){
        int pix = idx/11, q = idx - pix*11;
        int rr = pix/27, cc = pix - rr*27;
        int gr = r0row - 1 + rr, gc = cc - 1;
        float4 v = {0.f,0.f,0.f,0.f};
        if (q < 10 && (unsigned)gr < 25u && (unsigned)gc < 25u)
            v = *reinterpret_cast<const float4*>(ib + (size_t)(gr*25+gc)*CH + q*8);
        *reinterpret_cast<float4*>(at + pix*CHS + q*8) = v;
    }

    // per-lane m-tile pixel bases (A row = lane&31 within m-tile)
    int pm[4];
    #pragma unroll
    for (int mt = 0; mt < 4; ++mt){
        int m = mg*128 + mt*32 + (lane & 31);
        int row = m/25, col = m - row*25;
        pm[mt] = (row - r0row + 1)*27 + col;
    }
    const int kh8 = (lane >> 5)*8;            // k-half ch offset (A & B: k=(l>>5)*8+e)

    f32x16 acc[4];
    #pragma unroll
    for (int mt = 0; mt < 4; ++mt)
        #pragma unroll
        for (int e = 0; e < 16; ++e) acc[mt][e] = 0.f;

    __syncthreads();

    // ---- K loop: 9 taps x 5 ci, B 1-deep prefetched ----
    const bf16x8* wf = reinterpret_cast<const bf16x8*>(wpk) + nt*64 + lane;
    bf16x8 bcur = wf[0];
    #pragma unroll 1
    for (int tap = 0; tap < 9; ++tap){
        const int ky = (tap >= 6) ? 2 : (tap >= 3) ? 1 : 0;
        const int kx = tap - ky*3;
        const int off = (ky - 1)*27 + kx;
        const unsigned short* a0 = at + (pm[0]+off)*CHS + kh8;
        const unsigned short* a1 = at + (pm[1]+off)*CHS + kh8;
        const unsigned short* a2 = at + (pm[2]+off)*CHS + kh8;
        const unsigned short* a3 = at + (pm[3]+off)*CHS + kh8;
        #pragma unroll
        for (int ci = 0; ci < 5; ++ci){
            const int kb = tap*5 + ci;
            const int kn = (kb + 1 < NKB) ? kb + 1 : kb;
            bf16x8 bnxt = wf[(size_t)kn*512];                  // prefetch next B frag
            bf16x8 fa0 = *reinterpret_cast<const bf16x8*>(a0 + ci*16);
            bf16x8 fa1 = *reinterpret_cast<const bf16x8*>(a1 + ci*16);
            bf16x8 fa2 = *reinterpret_cast<const bf16x8*>(a2 + ci*16);
            bf16x8 fa3 = *reinterpret_cast<const bf16x8*>(a3 + ci*16);
            acc[0] = __builtin_amdgcn_mfma_f32_32x32x16_bf16(fa0, bcur, acc[0], 0,0,0);
            acc[1] = __builtin_amdgcn_mfma_f32_32x32x16_bf16(fa1, bcur, acc[1], 0,0,0);
            acc[2] = __builtin_amdgcn_mfma_f32_32x32x16_bf16(fa2, bcur, acc[2], 0,0,0);
            acc[3] = __builtin_amdgcn_mfma_f32_32x32x16_bf16(fa3, bcur, acc[3], 0,0,0);
            bcur = bnxt;
        }
    }

    // ---- fused LSTM epilogue ----
    // lane: g = lane&3 (0=i,1=f,2=o,3=g), j = nt*8 + (lane&31)>>2
    // C/D layout (m74): col = lane&31, m-row = (r&3) + 8*(r>>2) + 4*(lane>>5)
    const int g = lane & 3;
    const int j = nt*8 + ((lane & 31) >> 2);
    const float bown = bias[g*64 + j];
    const bool isg = (g == 3);
    const int mbase = mg*128 + 4*(lane >> 5);
    float* cb = cbuf + (size_t)b*PLANE*HID;
    float* hb = hbuf + (size_t)b*PLANE*HID;
    unsigned short* hn = inpn + (size_t)b*PLANE*CH;

    #pragma unroll
    for (int mt = 0; mt < 4; ++mt){
        #pragma unroll
        for (int r = 0; r < 16; ++r){
            float a   = acc[mt][r] + bown;
            float act = isg ? ftanh(a) : fsigm(a);
            float s1  = __shfl_xor(act, 1);   // partner gate g^1
            float s2  = __shfl_xor(act, 2);   // g^2
            float s3  = __shfl_xor(act, 3);   // g^3
            int   m   = mbase + mt*32 + (r & 3) + 8*(r >> 2);
            if (g == 0 && m < PLANE){
                // lane g=0: act=i, s1=f, s2=o, s3=g'
                float co = cb[m*HID + j];
                float cn = s1*co + act*s3;
                float h  = s2*ftanh(cn);
                cb[m*HID + j] = cn;
                hn[(size_t)m*CH + CIN + j] = f2bf(h);
                if (write_h) hb[m*HID + j] = h;
            }
        }
    }
}

// -------- MLP head: relu(h) -> 16 -> 8 -> 2 -> log_softmax (h layout [b][m][j]) --------
__global__ __launch_bounds__(256) void k_mlp(
    const float* __restrict__ hfin,
    const float* __restrict__ w1, const float* __restrict__ b1,
    const float* __restrict__ w2, const float* __restrict__ b2,
    const float* __restrict__ w3, const float* __restrict__ b3,
    float* __restrict__ out)
{
    __shared__ float red[256][17];
    __shared__ float hid1[16];
    __shared__ float hid2[8];
    const int b = blockIdx.x, tid = threadIdx.x;

    float acc[16];
    #pragma unroll
    for (int i = 0; i < 16; ++i) acc[i] = 0.f;

    const float* hbb = hfin + (size_t)b * (HID * PLANE);
    for (int kidx = tid; kidx < HID * PLANE; kidx += 256){
        int m = kidx >> 6, j = kidx & 63;
        float hv = hbb[kidx];                 // [m][j] layout
        hv = hv > 0.f ? hv : 0.f;
        const float* wf = w1 + (size_t)(j*PLANE + m) * 16;   // flatten k = j*625+m
        #pragma unroll
        for (int i = 0; i < 16; ++i) acc[i] = fmaf(hv, wf[i], acc[i]);
    }
    #pragma unroll
    for (int i = 0; i < 16; ++i) red[tid][i] = acc[i];
    __syncthreads();

    if (tid < 16){
        float s = b1[tid];
        for (int t2 = 0; t2 < 256; ++t2) s += red[t2][tid];
        hid1[tid] = s > 0.f ? s : 0.f;
    }
    __syncthreads();
    if (tid < 8){
        float s = b2[tid];
        #pragma unroll
        for (int k2 = 0; k2 < 16; ++k2) s += hid1[k2] * w2[k2*8 + tid];
        hid2[tid] = s > 0.f ? s : 0.f;
    }
    __syncthreads();
    if (tid == 0){
        float l0 = b3[0], l1 = b3[1];
        #pragma unroll
        for (int k3 = 0; k3 < 8; ++k3){ l0 += hid2[k3]*w3[k3*2]; l1 += hid2[k3]*w3[k3*2+1]; }
        float m   = fmaxf(l0, l1);
        float lse = m + logf(__expf(l0 - m) + __expf(l1 - m));
        out[b*2 + 0] = l0 - lse;
        out[b*2 + 1] = l1 - lse;
    }
}

extern "C" void kernel_launch(void* const* d_in, const int* in_sizes, int n_in,
                              void* d_out, int out_size, void* d_ws, size_t ws_size,
                              hipStream_t stream) {
    const float* x      = (const float*)d_in[0];
    const float* conv_w = (const float*)d_in[1];
    const float* conv_b = (const float*)d_in[2];
    const float* w1     = (const float*)d_in[3];
    const float* b1     = (const float*)d_in[4];
    const float* w2     = (const float*)d_in[5];
    const float* b2     = (const float*)d_in[6];
    const float* w3     = (const float*)d_in[7];
    const float* b3     = (const float*)d_in[8];
    float* out = (float*)d_out;

    // ws carve (~67 MB): inp0/inp1 bf16 12.8MB each, c 20.5MB, h 20.5MB, wpk 0.37MB
    unsigned short* inp0 = (unsigned short*)d_ws;
    unsigned short* inp1 = inp0 + INPSZ;
    float* c   = (float*)(inp1 + INPSZ);
    float* hb  = c + CSZ;
    unsigned short* wpk = (unsigned short*)(hb + CSZ);

    // ws poisoned 0xAA, not re-poisoned between replays -> re-init every call
    hipMemsetAsync(inp0, 0, (size_t)INPSZ*2, stream);   // zeros h-part(t=0) + ch pad
    hipMemsetAsync(inp1, 0, (size_t)INPSZ*2, stream);   // zeros ch pad
    hipMemsetAsync(c,    0, (size_t)CSZ*4,   stream);

    k_wprep<<<dim3(90),   dim3(256), 0, stream>>>(conv_w, wpk);
    k_xcopy<<<dim3(3125), dim3(256), 0, stream>>>(x, inp0, 0);

    for (int t = 0; t < TT; ++t){
        unsigned short* ic = (t & 1) ? inp1 : inp0;
        unsigned short* in_ = (t & 1) ? inp0 : inp1;
        k_gemm<<<dim3(5, BATCH), dim3(512), 0, stream>>>(ic, in_, wpk, conv_b, c, hb,
                                                         (t == TT-1) ? 1 : 0);
        if (t < TT-1)
            k_xcopy<<<dim3(3125), dim3(256), 0, stream>>>(x, in_, t + 1);
    }
    k_mlp<<<dim3(BATCH), dim3(256), 0, stream>>>(hb, w1, b1, w2, b2, w3, b3, out);
}

// Round 7
// 726.758 us; speedup vs baseline: 103.0746x; 1.8104x over previous
//
#include <hip/hip_runtime.h>
#include <hip/hip_bf16.h>
#include <math.h>

#define BATCH 128
#define TT    12
#define CIN   10
#define HID   64
#define PLANE 625
#define NU    10          // 16B channel-units per pixel (80 padded ch)
#define IPB   50000       // shorts per batch image in inp: NU*PLANE*8
#define NKB   45          // k-blocks: 9 taps * 5 chunks of 16 ch
#define CSZ   (BATCH*PLANE*HID)   // floats in c / h buffers

typedef __attribute__((ext_vector_type(8)))  short bf16x8;
typedef __attribute__((ext_vector_type(16))) float f32x16;

__device__ __forceinline__ float fsigm(float v){ return 1.f/(1.f+__expf(-v)); }
__device__ __forceinline__ float ftanh(float v){ return 1.f - 2.f/(__expf(2.f*v)+1.f); }
__device__ __forceinline__ unsigned short f2bf(float v){
    __hip_bfloat16 b = __float2bfloat16(v);
    return *reinterpret_cast<unsigned short*>(&b);
}

// ---- prepack conv_w (256,74,3,3) f32 -> B-fragments bf16 ----
// k = tap*80 + ch (tap = ky*3+kx), n-permutation: col = jlo*4 + g  (j = nt*8+jlo, o = g*64+j)
// frag layout (32x32x16 B): lane l: col = l&31, k_local = (l>>5)*8 + e
__global__ void k_wprep(const float* __restrict__ w, unsigned short* __restrict__ wpk){
    int tid = blockIdx.x*256 + threadIdx.x;      // NKB*8*64 = 23040 total
    if (tid >= NKB*8*64) return;
    int lane = tid & 63;
    int nt   = (tid >> 6) & 7;
    int kb   = tid >> 9;
    int tap = kb/5, ci = kb - tap*5;
    int ky = tap/3, kx = tap - ky*3;
    int g = lane & 3, jlo = (lane & 31) >> 2, kh = lane >> 5;
    int o = g*64 + nt*8 + jlo;
    union { unsigned short u[8]; float4 f; } pk;
    #pragma unroll
    for (int e = 0; e < 8; ++e){
        int ch = ci*16 + kh*8 + e;
        float v = (ch < 74) ? w[((o*74 + ch)*3 + ky)*3 + kx] : 0.f;
        pk.u[e] = f2bf(v);
    }
    *reinterpret_cast<float4*>(wpk + (size_t)tid*8) = pk.f;   // idx = (kb*8+nt)*64+lane
}

// ---- copy x_0 (f32 NCHW) into inp buffer x-slots (unit-major bf16 layout) ----
// inp layout: [b][u][625 pix][8 ch-slots], u = ch>>3
__global__ void k_xcopy(const float* __restrict__ x, unsigned short* __restrict__ inp, int t){
    int idx = blockIdx.x*256 + threadIdx.x;      // 128*10*625 = 800000
    if (idx >= BATCH*CIN*PLANE) return;
    int m  = idx % PLANE;
    int r  = idx / PLANE;
    int ch = r % CIN;
    int b  = r / CIN;
    float v = x[((size_t)(b*TT + t)*CIN + ch)*PLANE + m];
    inp[(size_t)b*IPB + ((((ch>>3)*PLANE) + m)<<3) + (ch&7)] = f2bf(v);
}

// ---- fused conv-as-GEMM (MFMA bf16) + LSTM pointwise + next-step x-copy ----
// block = (mgroup of 128 m, batch), 512 thr = 8 waves; wave = n-tile of 32.
// A-tile LDS layout [u][216 pix][16B]: conflict-free ds_read_b128 (consecutive pixels
// cover all 32 banks; round-6 layout cost exactly +4 cyc/read in conflicts).
// K-loop: ci unrolled w/ immediate ds offsets; tap loop unroll-1 w/ constant pointer
// increments; B via walking pointer + 1-deep prefetch (bounds reg pressure).
// Epilogue: in-register 4x4 quad transpose -> all 64 lanes do c-updates.
__global__ __launch_bounds__(512) void k_gemm(
    const float* __restrict__ x,
    const unsigned short* __restrict__ inp,   // step-t input, unit-major
    unsigned short* __restrict__ inpn,        // next-step buffer (h-part + x-part writes)
    const unsigned short* __restrict__ wpk,
    const float* __restrict__ bias,           // conv_b[256], o = g*64+j
    float* __restrict__ cbuf,                 // [b][625][64] fp32
    float* __restrict__ hbuf,                 // [b][625][64] fp32 (written at t=TT-1)
    int t)
{
    __shared__ __align__(16) unsigned short at2[2160*8];   // [10 u][216 pix][8], 34.56 KB

    const int tid  = threadIdx.x;
    const int mg   = blockIdx.x;              // 0..4 (128 m each; m 625..639 pad)
    const int b    = blockIdx.y;
    const int lane = tid & 63;
    const int nt   = tid >> 6;                // wave id = n-tile
    const int r0row = (mg*128)/25;            // 0,5,10,15,20

    // ---- stage A-tile: rows r0row-1..r0row+6, cols -1..25, zero halo/pad ----
    // idx = u*216 + pix: global reads pixel-consecutive 16B (coalesced),
    // LDS writes idx-consecutive 16B (conflict-free).
    const unsigned short* ib = inp + (size_t)b*IPB;
    for (int idx = tid; idx < 2160; idx += 512){
        int q   = idx/216, pix = idx - q*216;
        int rr  = pix/27,  cc  = pix - rr*27;
        int gr  = r0row - 1 + rr, gc = cc - 1;
        float4 v = {0.f,0.f,0.f,0.f};
        if ((unsigned)gr < 25u && (unsigned)gc < 25u)
            v = *reinterpret_cast<const float4*>(ib + (((size_t)q*PLANE + gr*25 + gc)<<3));
        *reinterpret_cast<float4*>(at2 + ((size_t)idx<<3)) = v;
    }

    // per-lane m-tile pixel bases (A row = lane&31 within m-tile)
    const int kh = lane >> 5;
    const unsigned short* ap[4];
    #pragma unroll
    for (int mt = 0; mt < 4; ++mt){
        int m = mg*128 + mt*32 + (lane & 31);
        int row = m/25, col = m - row*25;
        int pm = (row - r0row + 1)*27 + col;       // in [27, 213]
        ap[mt] = at2 + ((kh*216 + pm - 27) << 3);  // rebased so tap offsets >= 0
    }

    f32x16 acc[4];
    #pragma unroll
    for (int mt = 0; mt < 4; ++mt)
        #pragma unroll
        for (int e = 0; e < 16; ++e) acc[mt][e] = 0.f;

    __syncthreads();

    // ---- K loop: 9 taps x 5 ci ----
    const bf16x8* wptr = reinterpret_cast<const bf16x8*>(wpk) + nt*64 + lane;
    bf16x8 bcur = *wptr;
    const unsigned short *a0 = ap[0], *a1 = ap[1], *a2 = ap[2], *a3 = ap[3];
    #pragma unroll 1
    for (int tap = 0; tap < 9; ++tap){
        #pragma unroll
        for (int ci = 0; ci < 5; ++ci){
            bf16x8 bnxt = wptr[512];               // 1-deep prefetch (last reads slack)
            wptr += 512;
            bf16x8 f0 = *reinterpret_cast<const bf16x8*>(a0 + ci*3456);  // imm offsets
            bf16x8 f1 = *reinterpret_cast<const bf16x8*>(a1 + ci*3456);
            bf16x8 f2 = *reinterpret_cast<const bf16x8*>(a2 + ci*3456);
            bf16x8 f3 = *reinterpret_cast<const bf16x8*>(a3 + ci*3456);
            acc[0] = __builtin_amdgcn_mfma_f32_32x32x16_bf16(f0, bcur, acc[0], 0,0,0);
            acc[1] = __builtin_amdgcn_mfma_f32_32x32x16_bf16(f1, bcur, acc[1], 0,0,0);
            acc[2] = __builtin_amdgcn_mfma_f32_32x32x16_bf16(f2, bcur, acc[2], 0,0,0);
            acc[3] = __builtin_amdgcn_mfma_f32_32x32x16_bf16(f3, bcur, acc[3], 0,0,0);
            bcur = bnxt;
        }
        const int d = (tap == 2 || tap == 5) ? 25*8 : 8;   // toff delta in shorts
        a0 += d; a1 += d; a2 += d; a3 += d;
    }

    // ---- fused LSTM epilogue: quad transpose -> all lanes update ----
    // pre-transpose: lane (g=lane&3) holds gate g for elements e=0..3 of quad rq.
    // post-transpose: lane g holds gates i,f,o,g~ of element e=g.
    // m = mbase + mt*32 + g + 8*rq (C/D m-row = (r&3) + 8*(r>>2) + 4*kh, r = rq*4+e)
    const int g   = lane & 3;
    const int jlo = (lane & 31) >> 2;
    const int j   = nt*8 + jlo;
    const float bown = bias[g*64 + j];
    const float sA = (g == 3) ? 2.f : 1.f;    // act = sA*sigm(sA*x) + sB (tanh when g=3)
    const float sB = (g == 3) ? -1.f : 0.f;
    const int  mbase = mg*128 + 4*kh;
    const bool gb0 = (g & 1), gb1 = (g & 2);
    float* cb = cbuf + (size_t)b*PLANE*HID;
    float* hb = hbuf + (size_t)b*PLANE*HID;
    unsigned short* hn = inpn + (size_t)b*IPB;
    const int chh = CIN + j, uh = chh >> 3, sh = chh & 7;

    #pragma unroll
    for (int mt = 0; mt < 4; ++mt){
        #pragma unroll
        for (int rq = 0; rq < 4; ++rq){
            float v0 = fmaf(sA, fsigm(sA*(acc[mt][rq*4+0] + bown)), sB);
            float v1 = fmaf(sA, fsigm(sA*(acc[mt][rq*4+1] + bown)), sB);
            float v2 = fmaf(sA, fsigm(sA*(acc[mt][rq*4+2] + bown)), sB);
            float v3 = fmaf(sA, fsigm(sA*(acc[mt][rq*4+3] + bown)), sB);
            float s;
            s = __shfl_xor(gb0 ? v0 : v1, 1); if (gb0) v0 = s; else v1 = s;
            s = __shfl_xor(gb0 ? v2 : v3, 1); if (gb0) v2 = s; else v3 = s;
            s = __shfl_xor(gb1 ? v0 : v2, 2); if (gb1) v0 = s; else v2 = s;
            s = __shfl_xor(gb1 ? v1 : v3, 2); if (gb1) v1 = s; else v3 = s;
            // now v0=i, v1=f, v2=o, v3=g~ of element m below
            const int m = mbase + mt*32 + g + 8*rq;
            if (m < PLANE){
                float co = cb[m*HID + j];
                float cn = fmaf(v1, co, v0*v3);
                float h  = v2 * ftanh(cn);
                cb[m*HID + j] = cn;
                hn[((uh*PLANE + m) << 3) + sh] = f2bf(h);
                if (t == TT-1) hb[m*HID + j] = h;
            }
        }
    }

    // ---- fused x-copy for step t+1 (this block's m-slice) ----
    if (t < TT-1){
        const float* xn = x + (size_t)(b*TT + t + 1)*CIN*PLANE;
        for (int idx = tid; idx < 1280; idx += 512){
            int ch = idx >> 7, mi = idx & 127;
            int m = mg*128 + mi;
            if (m < PLANE)
                inpn[(size_t)b*IPB + ((((ch>>3)*PLANE) + m)<<3) + (ch&7)] =
                    f2bf(xn[ch*PLANE + m]);
        }
    }
}

// -------- MLP head: relu(h) -> 16 -> 8 -> 2 -> log_softmax (h layout [b][m][j]) --------
__global__ __launch_bounds__(256) void k_mlp(
    const float* __restrict__ hfin,
    const float* __restrict__ w1, const float* __restrict__ b1,
    const float* __restrict__ w2, const float* __restrict__ b2,
    const float* __restrict__ w3, const float* __restrict__ b3,
    float* __restrict__ out)
{
    __shared__ float red[256][17];
    __shared__ float hid1[16];
    __shared__ float hid2[8];
    const int b = blockIdx.x, tid = threadIdx.x;

    float acc[16];
    #pragma unroll
    for (int i = 0; i < 16; ++i) acc[i] = 0.f;

    const float* hbb = hfin + (size_t)b * (HID * PLANE);
    for (int kidx = tid; kidx < HID * PLANE; kidx += 256){
        int m = kidx >> 6, j = kidx & 63;
        float hv = hbb[kidx];                 // [m][j] layout
        hv = hv > 0.f ? hv : 0.f;
        const float* wf = w1 + (size_t)(j*PLANE + m) * 16;   // flatten k = j*625+m
        #pragma unroll
        for (int i = 0; i < 16; ++i) acc[i] = fmaf(hv, wf[i], acc[i]);
    }
    #pragma unroll
    for (int i = 0; i < 16; ++i) red[tid][i] = acc[i];
    __syncthreads();

    if (tid < 16){
        float s = b1[tid];
        for (int t2 = 0; t2 < 256; ++t2) s += red[t2][tid];
        hid1[tid] = s > 0.f ? s : 0.f;
    }
    __syncthreads();
    if (tid < 8){
        float s = b2[tid];
        #pragma unroll
        for (int k2 = 0; k2 < 16; ++k2) s += hid1[k2] * w2[k2*8 + tid];
        hid2[tid] = s > 0.f ? s : 0.f;
    }
    __syncthreads();
    if (tid == 0){
        float l0 = b3[0], l1 = b3[1];
        #pragma unroll
        for (int k3 = 0; k3 < 8; ++k3){ l0 += hid2[k3]*w3[k3*2]; l1 += hid2[k3]*w3[k3*2+1]; }
        float m   = fmaxf(l0, l1);
        float lse = m + logf(__expf(l0 - m) + __expf(l1 - m));
        out[b*2 + 0] = l0 - lse;
        out[b*2 + 1] = l1 - lse;
    }
}

extern "C" void kernel_launch(void* const* d_in, const int* in_sizes, int n_in,
                              void* d_out, int out_size, void* d_ws, size_t ws_size,
                              hipStream_t stream) {
    const float* x      = (const float*)d_in[0];
    const float* conv_w = (const float*)d_in[1];
    const float* conv_b = (const float*)d_in[2];
    const float* w1     = (const float*)d_in[3];
    const float* b1     = (const float*)d_in[4];
    const float* w2     = (const float*)d_in[5];
    const float* b2     = (const float*)d_in[6];
    const float* w3     = (const float*)d_in[7];
    const float* b3     = (const float*)d_in[8];
    float* out = (float*)d_out;

    // ws carve (~67 MB): inp0/inp1 bf16 12.8MB each, c 20.5MB, h 20.5MB, wpk 0.38MB
    unsigned short* inp0 = (unsigned short*)d_ws;
    unsigned short* inp1 = inp0 + (size_t)BATCH*IPB;
    float* c   = (float*)(inp1 + (size_t)BATCH*IPB);
    float* hb  = c + CSZ;
    unsigned short* wpk = (unsigned short*)(hb + CSZ);   // NKB frags + 1 slack frag

    // ws poisoned 0xAA, not re-poisoned between replays -> re-init every call
    hipMemsetAsync(inp0, 0, (size_t)BATCH*IPB*2, stream);   // zeros h(t=0) + ch pad
    hipMemsetAsync(inp1, 0, (size_t)BATCH*IPB*2, stream);   // zeros ch pad
    hipMemsetAsync(c,    0, (size_t)CSZ*4,       stream);

    k_wprep<<<dim3(90),   dim3(256), 0, stream>>>(conv_w, wpk);
    k_xcopy<<<dim3(3125), dim3(256), 0, stream>>>(x, inp0, 0);

    for (int t = 0; t < TT; ++t){
        unsigned short* ic  = (t & 1) ? inp1 : inp0;
        unsigned short* in_ = (t & 1) ? inp0 : inp1;
        k_gemm<<<dim3(5, BATCH), dim3(512), 0, stream>>>(x, ic, in_, wpk, conv_b, c, hb, t);
    }
    k_mlp<<<dim3(BATCH), dim3(256), 0, stream>>>(hb, w1, b1, w2, b2, w3, b3, out);
}